// Round 8
// baseline (530.048 us; speedup 1.0000x reference)
//
#include <hip/hip_runtime.h>
#include <cstdint>
#include <cstddef>

// ---------------------------------------------------------------------------
// TransformerEncoderLayer on MI355X (gfx950)
// B=2, S=2048, D_MODEL=1024, 16 heads x 64, VOCAB=32000, PAD=0
// bf16 MFMA for all GEMMs + flash attention; fp32 LN / residual streams.
// R12 = R11 + BK=128 in gemm_bt64 (FFN-down was top kernel at 75.6us,
//     latency-bound: 64 iterations x {stage -> vmcnt(0) drain at barrier ->
//     16 MFMA}, grid-limited to 2 blocks/CU). Doubling the K-step halves the
//     number of latency exposures (64->32 iters for K=4096) while keeping the
//     proven single-buffer 2-barrier template (no new sync semantics).
//     LDS 48KB (<64KB limit). Everything else identical to R11.
// ---------------------------------------------------------------------------

#define SEQ     2048
#define NTOK    4096          // B*S
#define DMODEL  1024
#define NHEAD   16
#define DHEAD   64
#define MASKV   (-30.0f)      // soft mask: exp(-30)~1e-13, exact softmax ratios
#define LN_EPS  1e-5f

typedef __bf16 bf16_t;
typedef __bf16 bf16x8 __attribute__((ext_vector_type(8)));
typedef float  f32x4  __attribute__((ext_vector_type(4)));

#define MFMA_BF16(a,b,c) __builtin_amdgcn_mfma_f32_16x16x32_bf16((a),(b),(c),0,0,0)

__device__ __forceinline__ void gload_lds16(const void* g, void* l) {
  __builtin_amdgcn_global_load_lds(
      (__attribute__((address_space(1))) void*)(g),
      (__attribute__((address_space(3))) void*)(l), 16, 0, 0);
}

// ---------------- weight transpose+convert: W[K][N] f32 -> WT[N][K] bf16 ----
__global__ __launch_bounds__(256)
void wtrans_kernel(const float* __restrict__ W, bf16_t* __restrict__ WT,
                   int K, int N) {
  __shared__ float tile[64][65];
  const int n0 = blockIdx.x * 64, k0 = blockIdx.y * 64;
  const int c = threadIdx.x & 63, rb = threadIdx.x >> 6;
#pragma unroll
  for (int i = 0; i < 16; ++i) {
    int r = i * 4 + rb;
    tile[r][c] = W[(size_t)(k0 + r) * N + n0 + c];
  }
  __syncthreads();
#pragma unroll
  for (int i = 0; i < 16; ++i) {
    int r = i * 4 + rb;                       // output row (n), col (k)
    WT[(size_t)(n0 + r) * K + k0 + c] = (bf16_t)tile[c][r];
  }
}

__global__ __launch_bounds__(256)
void pack_bias_kernel(const float* __restrict__ bq, const float* __restrict__ bk,
                      const float* __restrict__ bv, float* __restrict__ o) {
  int i = blockIdx.x * 256 + threadIdx.x;
  if (i < 1024) { o[i] = bq[i]; o[1024 + i] = bk[i]; o[2048 + i] = bv[i]; }
}

// ---------------- embed + pos + LN1 -> x_ln f32, x_ln bf16 ------------------
__global__ __launch_bounds__(256)
void ln1_kernel(const int* __restrict__ tokens, const float* __restrict__ emb,
                const float* __restrict__ pos, const float* __restrict__ g,
                const float* __restrict__ bb, float* __restrict__ xln,
                bf16_t* __restrict__ xlnb) {
  __shared__ float red[8];
  const int t = blockIdx.x;
  const int s = t & (SEQ - 1);
  const int tok = tokens[t];
  const int d0 = threadIdx.x * 4;
  const int w = threadIdx.x >> 6, lane = threadIdx.x & 63;

  float4 e  = *(const float4*)(emb + (size_t)tok * DMODEL + d0);
  float4 pp = *(const float4*)(pos + (size_t)s   * DMODEL + d0);
  float x0 = e.x + pp.x, x1 = e.y + pp.y, x2v = e.z + pp.z, x3v = e.w + pp.w;
  float s1 = x0 + x1 + x2v + x3v;
  float s2 = x0*x0 + x1*x1 + x2v*x2v + x3v*x3v;
#pragma unroll
  for (int o = 32; o >= 1; o >>= 1) { s1 += __shfl_xor(s1, o); s2 += __shfl_xor(s2, o); }
  if (lane == 0) { red[w] = s1; red[4 + w] = s2; }
  __syncthreads();
  s1 = red[0] + red[1] + red[2] + red[3];
  s2 = red[4] + red[5] + red[6] + red[7];
  float mean = s1 * (1.0f / DMODEL);
  float var  = s2 * (1.0f / DMODEL) - mean * mean;
  float inv  = rsqrtf(var + LN_EPS);
  float4 gv = *(const float4*)(g + d0);
  float4 bv = *(const float4*)(bb + d0);
  float y0 = (x0  - mean) * inv * gv.x + bv.x;
  float y1 = (x1  - mean) * inv * gv.y + bv.y;
  float y2 = (x2v - mean) * inv * gv.z + bv.z;
  float y3 = (x3v - mean) * inv * gv.w + bv.w;
  *(float4*)(xln + (size_t)t * DMODEL + d0) = make_float4(y0, y1, y2, y3);
  union { ushort4 u; bf16_t b[4]; } cv;
  cv.b[0] = (bf16_t)y0; cv.b[1] = (bf16_t)y1; cv.b[2] = (bf16_t)y2; cv.b[3] = (bf16_t)y3;
  *(ushort4*)(xlnb + (size_t)t * DMODEL + d0) = cv.u;
}

// -------- x2 = x_ln + LN2(attn_out); x3b = bf16(LN3(x2)) --------------------
__global__ __launch_bounds__(256)
void ln23_kernel(const float* __restrict__ ao, const float* __restrict__ xln,
                 const float* __restrict__ g2, const float* __restrict__ bb2,
                 const float* __restrict__ g3, const float* __restrict__ bb3,
                 float* __restrict__ x2o, bf16_t* __restrict__ x3b) {
  __shared__ float red[8];
  const int t = blockIdx.x;
  const int d0 = threadIdx.x * 4;
  const int w = threadIdx.x >> 6, lane = threadIdx.x & 63;

  float4 a = *(const float4*)(ao + (size_t)t * DMODEL + d0);
  float s1 = a.x + a.y + a.z + a.w;
  float s2 = a.x*a.x + a.y*a.y + a.z*a.z + a.w*a.w;
#pragma unroll
  for (int o = 32; o >= 1; o >>= 1) { s1 += __shfl_xor(s1, o); s2 += __shfl_xor(s2, o); }
  if (lane == 0) { red[w] = s1; red[4 + w] = s2; }
  __syncthreads();
  s1 = red[0] + red[1] + red[2] + red[3];
  s2 = red[4] + red[5] + red[6] + red[7];
  float mean = s1 * (1.0f / DMODEL);
  float var  = s2 * (1.0f / DMODEL) - mean * mean;
  float inv  = rsqrtf(var + LN_EPS);
  float4 gv = *(const float4*)(g2 + d0);
  float4 bv = *(const float4*)(bb2 + d0);
  float4 xv = *(const float4*)(xln + (size_t)t * DMODEL + d0);
  float y0 = xv.x + (a.x - mean) * inv * gv.x + bv.x;
  float y1 = xv.y + (a.y - mean) * inv * gv.y + bv.y;
  float y2 = xv.z + (a.z - mean) * inv * gv.z + bv.z;
  float y3 = xv.w + (a.w - mean) * inv * gv.w + bv.w;
  *(float4*)(x2o + (size_t)t * DMODEL + d0) = make_float4(y0, y1, y2, y3);

  // second LN (LN3) on x2
  float t1 = y0 + y1 + y2 + y3;
  float t2 = y0*y0 + y1*y1 + y2*y2 + y3*y3;
#pragma unroll
  for (int o = 32; o >= 1; o >>= 1) { t1 += __shfl_xor(t1, o); t2 += __shfl_xor(t2, o); }
  __syncthreads();                         // all phase-1 reads of red[] done
  if (lane == 0) { red[w] = t1; red[4 + w] = t2; }
  __syncthreads();
  t1 = red[0] + red[1] + red[2] + red[3];
  t2 = red[4] + red[5] + red[6] + red[7];
  float mean2 = t1 * (1.0f / DMODEL);
  float var2  = t2 * (1.0f / DMODEL) - mean2 * mean2;
  float inv2  = rsqrtf(var2 + LN_EPS);
  float4 gv3 = *(const float4*)(g3 + d0);
  float4 bv3 = *(const float4*)(bb3 + d0);
  union { ushort4 u; bf16_t b[4]; } cv;
  cv.b[0] = (bf16_t)((y0 - mean2) * inv2 * gv3.x + bv3.x);
  cv.b[1] = (bf16_t)((y1 - mean2) * inv2 * gv3.y + bv3.y);
  cv.b[2] = (bf16_t)((y2 - mean2) * inv2 * gv3.z + bv3.z);
  cv.b[3] = (bf16_t)((y3 - mean2) * inv2 * gv3.w + bv3.w);
  *(ushort4*)(x3b + (size_t)t * DMODEL + d0) = cv.u;
}

// ---------------- generic TN bf16 GEMM: C = A[M,K] @ B[N,K]^T + bias --------
// EPI: 0 = bf16 store, 1 = f32 store, 2 = tanh-GELU + bf16, 3 = +res f32
constexpr int EPI_BF16 = 0, EPI_F32 = 1, EPI_GELU = 2, EPI_RES = 3;

// gelu(v) ~= v * sigmoid(1.5957691*v + 0.07135482*v^3); max err ~3e-4
__device__ __forceinline__ float gelu_fast(float v) {
  float u = v * (1.5957691216f + 0.0713548163f * v * v);
  return v * __frcp_rn(1.0f + __expf(-u));
}

template <int EPI>
__global__ __launch_bounds__(256, 4)
void gemm_bt(const bf16_t* __restrict__ A, const bf16_t* __restrict__ B,
             const float* __restrict__ bias, const float* __restrict__ res,
             bf16_t* __restrict__ obf, float* __restrict__ of32,
             int M, int N, int K) {
  __shared__ __attribute__((aligned(16))) bf16_t As[128 * 64];
  __shared__ __attribute__((aligned(16))) bf16_t Bs[128 * 64];
  const int tid = threadIdx.x;
  const int w = tid >> 6, lane = tid & 63;
  const int quad = lane >> 4, l16 = lane & 15;
  const int m0 = blockIdx.x * 128, n0 = blockIdx.y * 128;
  const int wm = (w >> 1) * 64, wn = (w & 1) * 64;
  const size_t Kz = (size_t)K;

  f32x4 acc[4][4] = {};

  const bf16_t* Ag = A + (size_t)(m0 + w * 32 + (lane >> 3)) * Kz + (lane & 7) * 8;
  const bf16_t* Bg = B + (size_t)(n0 + w * 32 + (lane >> 3)) * Kz + (lane & 7) * 8;
  bf16_t* Asw = &As[(w * 32) * 64];
  bf16_t* Bsw = &Bs[(w * 32) * 64];

  for (int k0 = 0; k0 < K; k0 += 64) {
#pragma unroll
    for (int i = 0; i < 4; ++i) {
      gload_lds16(Ag + (size_t)i * 8 * Kz + k0, Asw + i * 8 * 64);
      gload_lds16(Bg + (size_t)i * 8 * Kz + k0, Bsw + i * 8 * 64);
    }
    __syncthreads();
#pragma unroll
    for (int kc = 0; kc < 2; ++kc) {
      bf16x8 af[4], bfr[4];
#pragma unroll
      for (int i = 0; i < 4; ++i) {
        af[i]  = *(const bf16x8*)&As[(wm + i * 16 + l16) * 64 + kc * 32 + quad * 8];
        bfr[i] = *(const bf16x8*)&Bs[(wn + i * 16 + l16) * 64 + kc * 32 + quad * 8];
      }
#pragma unroll
      for (int mi = 0; mi < 4; ++mi)
#pragma unroll
        for (int ni = 0; ni < 4; ++ni)
          acc[mi][ni] = MFMA_BF16(af[mi], bfr[ni], acc[mi][ni]);
    }
    __syncthreads();
  }

#pragma unroll
  for (int ni = 0; ni < 4; ++ni) {
    const int col = n0 + wn + ni * 16 + l16;
    const float bv = bias[col];
#pragma unroll
    for (int mi = 0; mi < 4; ++mi) {
#pragma unroll
      for (int r = 0; r < 4; ++r) {
        const int row = m0 + wm + mi * 16 + quad * 4 + r;
        float v = acc[mi][ni][r] + bv;
        if constexpr (EPI == EPI_GELU)
          v = gelu_fast(v);
        if constexpr (EPI == EPI_RES)
          v += res[(size_t)row * N + col];
        if constexpr (EPI == EPI_BF16 || EPI == EPI_GELU)
          obf[(size_t)row * N + col] = (bf16_t)v;
        else
          of32[(size_t)row * N + col] = v;
      }
    }
  }
}

// -------- 128x64-tile TN GEMM, BK=128 (for N=1024 GEMMs): 512 blocks --------
// Proven single-buffer 2-barrier loop, doubled K-step: per iteration stage
// 12 x 16B/lane loads then run 32 MFMA -> half the latency exposures of
// BK=64. LDS 48KB. 4 waves x 32 rows sharing the 64-col B panel.
template <int EPI>
__global__ __launch_bounds__(256, 4)
void gemm_bt64(const bf16_t* __restrict__ A, const bf16_t* __restrict__ B,
               const float* __restrict__ bias, const float* __restrict__ res,
               bf16_t* __restrict__ obf, float* __restrict__ of32,
               int M, int N, int K) {
  __shared__ __attribute__((aligned(16))) bf16_t As[128 * 128];   // 32 KB
  __shared__ __attribute__((aligned(16))) bf16_t Bs[64 * 128];    // 16 KB
  const int tid = threadIdx.x;
  const int w = tid >> 6, lane = tid & 63;
  const int quad = lane >> 4, l16 = lane & 15;
  const int m0 = blockIdx.x * 128, n0 = blockIdx.y * 64;
  const int wm = w * 32;
  const size_t Kz = (size_t)K;

  f32x4 acc[2][4] = {};

  // staging addressing (BK=128): lane>>4 = row-in-group-of-4, lane&15 = 16B
  // chunk; each gload covers 4 rows x 128 cols, LDS dest linear (stride 256B)
  const bf16_t* Ag = A + (size_t)(m0 + w * 32 + (lane >> 4)) * Kz + (lane & 15) * 8;
  const bf16_t* Bg = B + (size_t)(n0 + w * 16 + (lane >> 4)) * Kz + (lane & 15) * 8;
  bf16_t* Asw = &As[(w * 32) * 128];
  bf16_t* Bsw = &Bs[(w * 16) * 128];

  for (int k0 = 0; k0 < K; k0 += 128) {
#pragma unroll
    for (int i = 0; i < 8; ++i)
      gload_lds16(Ag + (size_t)i * 4 * Kz + k0, Asw + i * 4 * 128);
#pragma unroll
    for (int i = 0; i < 4; ++i)
      gload_lds16(Bg + (size_t)i * 4 * Kz + k0, Bsw + i * 4 * 128);
    __syncthreads();
#pragma unroll
    for (int kc = 0; kc < 4; ++kc) {
      bf16x8 af[2], bfr[4];
#pragma unroll
      for (int i = 0; i < 2; ++i)
        af[i]  = *(const bf16x8*)&As[(wm + i * 16 + l16) * 128 + kc * 32 + quad * 8];
#pragma unroll
      for (int i = 0; i < 4; ++i)
        bfr[i] = *(const bf16x8*)&Bs[(i * 16 + l16) * 128 + kc * 32 + quad * 8];
#pragma unroll
      for (int mi = 0; mi < 2; ++mi)
#pragma unroll
        for (int ni = 0; ni < 4; ++ni)
          acc[mi][ni] = MFMA_BF16(af[mi], bfr[ni], acc[mi][ni]);
    }
    __syncthreads();
  }

#pragma unroll
  for (int ni = 0; ni < 4; ++ni) {
    const int col = n0 + ni * 16 + l16;
    const float bv = bias[col];
#pragma unroll
    for (int mi = 0; mi < 2; ++mi) {
#pragma unroll
      for (int r = 0; r < 4; ++r) {
        const int row = m0 + wm + mi * 16 + quad * 4 + r;
        float v = acc[mi][ni][r] + bv;
        if constexpr (EPI == EPI_GELU)
          v = gelu_fast(v);
        if constexpr (EPI == EPI_RES)
          v += res[(size_t)row * N + col];
        if constexpr (EPI == EPI_BF16 || EPI == EPI_GELU)
          obf[(size_t)row * N + col] = (bf16_t)v;
        else
          of32[(size_t)row * N + col] = v;
      }
    }
  }
}

// ------ V transpose: qkv V-part [tok][h*64+d] -> Vt[bh][d][s], SWIZZLED -----
// Within each 128-key tile, 16B chunk k of d-row is stored at chunk k^(d&7),
// so attn can stage it linearly with global_load_lds and read conflict-free.
__global__ __launch_bounds__(256)
void vtrans_kernel(const bf16_t* __restrict__ qkv, bf16_t* __restrict__ Vt) {
  __shared__ bf16_t tile[128][72];          // [s_local][d]
  const int bh = blockIdx.y;
  const int b = bh >> 4, h = bh & 15;
  const int s0 = blockIdx.x * 128;
  const int c = threadIdx.x & 63, rb = threadIdx.x >> 6;
#pragma unroll
  for (int i = 0; i < 32; ++i) {
    int r = i * 4 + rb;                       // s-local 0..127
    tile[r][c] = qkv[(size_t)(b * SEQ + s0 + r) * 3072 + 2048 + h * 64 + c];
  }
  __syncthreads();
  const int d = threadIdx.x >> 2;             // 0..63
  const int k4 = threadIdx.x & 3;
#pragma unroll
  for (int kk = 0; kk < 4; ++kk) {
    const int k = kk * 4 + k4;                // chunk 0..15 (8 keys each)
    union { uint4 u; bf16_t bv[8]; } vv;
#pragma unroll
    for (int e = 0; e < 8; ++e) vv.bv[e] = tile[k * 8 + e][d];
    *(uint4*)(Vt + (size_t)(bh * 64 + d) * SEQ + s0 + ((k ^ (d & 7)) << 3)) = vv.u;
  }
}

// ---------------- flash attention, causal + key pad mask --------------------
// Per wave, 32 q-rows. Double-buffered LDS staging (2-phase), register
// softmax, no cross-lane ops:
//   S^T = mfma(K, Q) with permuted K rows: block 2c+e, A-row a <- key
//         32c + 8*(a>>2) + 2*(a&3) + e -> lane (quad,l16) holds even keys
//         8*quad+2r in sc[2c][r], odd in sc[2c+1][r]; PV B-fragment dword m
//         = pack(sc[2c][m], sc[2c+1][m]) by construction.
//   pad + causal applied at exp time (token loads off the MFMA path)
//   O^T += mfma(V^T, P^T);  l via ones-MFMA.

__device__ __forceinline__ unsigned pack2_bf16(float e, float o) {
  union { bf16_t b; unsigned short s; } lo, hi;
  lo.b = (bf16_t)e; hi.b = (bf16_t)o;
  return (unsigned)lo.s | ((unsigned)hi.s << 16);
}

__device__ __forceinline__ int tok_at(const int4& a, const int4& b, int j) {
  switch (j) {
    case 0: return a.x; case 1: return a.y; case 2: return a.z; case 3: return a.w;
    case 4: return b.x; case 5: return b.y; case 6: return b.z; default: return b.w;
  }
}

template <bool DIAG>
__device__ __forceinline__ void attn_tile(
    const bf16_t* __restrict__ Ksb, const bf16_t* __restrict__ Vsb,
    int k0, int chunkCnt, int w, int quad, int l16, int krow, int xr0,
    const int* __restrict__ tokb,
    const bf16x8 (&qf)[2][2], bf16x8 onev,
    f32x4 (&oacc)[2][4], f32x4 (&lacc)[2]) {

  // early token loads for pad mask (used at exp time)
  int4 tA[4], tB[4];
#pragma unroll
  for (int c = 0; c < 4; ++c)
    if (!DIAG || c < chunkCnt) {
      tA[c] = *(const int4*)(tokb + k0 + 32 * c + 8 * quad);
      tB[c] = *(const int4*)(tokb + k0 + 32 * c + 8 * quad + 4);
    }

  f32x4 sc0[8] = {}, sc1[8] = {};

  // S^T = (0.125*Q)K^T : A = permuted K rows from LDS (swizzled chunks)
#pragma unroll
  for (int kc = 0; kc < 2; ++kc)
#pragma unroll
    for (int ni = 0; ni < 8; ++ni)
      if (!DIAG || ni < 2 * chunkCnt) {
        const int r = 32 * (ni >> 1) + (ni & 1) + krow;
        bf16x8 kf = *(const bf16x8*)&Ksb[r * 64
            + (((kc * 4 + quad) ^ (xr0 + (ni & 1))) << 3)];
        sc0[ni] = MFMA_BF16(kf, qf[0][kc], sc0[ni]);
        sc1[ni] = MFMA_BF16(kf, qf[1][kc], sc1[ni]);
      }

  // pad + causal + exp; overwrite sc with P
#pragma unroll
  for (int mi = 0; mi < 2; ++mi) {
    f32x4* sc = mi ? sc1 : sc0;
    const int ql = w * 32 + mi * 16 + l16;       // q local to strip
#pragma unroll
    for (int ni = 0; ni < 8; ++ni)
      if (!DIAG || ni < 2 * chunkCnt) {
        const int c = ni >> 1, e = ni & 1;
#pragma unroll
        for (int r = 0; r < 4; ++r) {
          float v = sc[ni][r];
          if (tok_at(tA[c], tB[c], 2 * r + e) == 0) v += MASKV;
          if (DIAG) {
            int keyl = 32 * c + e + 8 * quad + 2 * r;
            if (keyl > ql) v += MASKV;
          }
          sc[ni][r] = __expf(v);
        }
      }
  }

  // O^T += V^T @ P^T ; l via ones-MFMA (D[r][q] = l[q] for every r).
#pragma unroll
  for (int c = 0; c < 4; ++c)
    if (!DIAG || c < chunkCnt) {
      union { unsigned u[4]; bf16x8 v; } pb0, pb1;
#pragma unroll
      for (int m = 0; m < 4; ++m) {
        pb0.u[m] = pack2_bf16(sc0[2 * c][m], sc0[2 * c + 1][m]);
        pb1.u[m] = pack2_bf16(sc1[2 * c][m], sc1[2 * c + 1][m]);
      }
      lacc[0] = MFMA_BF16(onev, pb0.v, lacc[0]);
      lacc[1] = MFMA_BF16(onev, pb1.v, lacc[1]);
#pragma unroll
      for (int nd = 0; nd < 4; ++nd) {
        bf16x8 vf = *(const bf16x8*)&Vsb[(nd * 16 + l16) * 128
            + (((c * 4 + quad) ^ (l16 & 7)) << 3)];
        oacc[0][nd] = MFMA_BF16(vf, pb0.v, oacc[0][nd]);
        oacc[1][nd] = MFMA_BF16(vf, pb1.v, oacc[1][nd]);
      }
    }
}

__global__ __launch_bounds__(256, 2)
void attn_kernel(const bf16_t* __restrict__ qkv, const bf16_t* __restrict__ Vt,
                 const int* __restrict__ tokens, bf16_t* __restrict__ attnb) {
  __shared__ __attribute__((aligned(16))) bf16_t Ks[2][128 * 64];   // 32 KB
  __shared__ __attribute__((aligned(16))) bf16_t Vs[2][64 * 128];   // 32 KB

  const int tid = threadIdx.x;
  const int w = tid >> 6, lane = tid & 63;
  const int quad = lane >> 4, l16 = lane & 15;
  const int bh = blockIdx.x;
  const int by = (int)blockIdx.y;
  // balanced pairing: CU pair gets strips s and 15-s (17 tiles total)
  const int strip = (by < 8) ? (15 - by) : (by - 8);
  const int b = bh >> 4, h = bh & 15;
  const int ntiles = strip + 1;
  const int qrow0 = strip * 128 + w * 32;    // this wave's 32 q-rows
  const int krow = ((l16 >> 2) << 3) + ((l16 & 3) << 1);
  const int xr0 = (l16 & 3) << 1;            // (permuted row)&7 = xr0 + e
  const int sw_chunk = (lane & 7) ^ ((lane >> 3) & 7);

  const bf16_t* Kbase = qkv + (size_t)b * SEQ * 3072 + 1024 + h * 64;
  const bf16_t* Vbase = Vt + (size_t)bh * 64 * SEQ;   // pre-swizzled content
  const int*    tokb  = tokens + b * SEQ;

  // Q fragments (B-operand: col=q=l16, k=quad*8+j), pre-scaled by 0.125
  bf16x8 qf[2][2];
#pragma unroll
  for (int mi = 0; mi < 2; ++mi) {
    const size_t trow = (size_t)(b * SEQ + qrow0 + mi * 16 + l16) * 3072 + h * 64;
    qf[mi][0] = *(const bf16x8*)(qkv + trow + quad * 8);
    qf[mi][1] = *(const bf16x8*)(qkv + trow + 32 + quad * 8);
  }
#pragma unroll
  for (int mi = 0; mi < 2; ++mi)
#pragma unroll
    for (int kc = 0; kc < 2; ++kc)
#pragma unroll
      for (int j = 0; j < 8; ++j)
        qf[mi][kc][j] = (bf16_t)((float)qf[mi][kc][j] * 0.125f);

  bf16x8 onev;
#pragma unroll
  for (int j = 0; j < 8; ++j) onev[j] = (bf16_t)1.0f;

  f32x4 oacc[2][4] = {};   // O^T: row=d (quad*4+r within nd), col=q (l16)
  f32x4 lacc[2] = {};

  // staging: wave w stages K rows [w*32,w*32+32) (source pre-swizzled chunks)
  // and V d-rows [w*16,w*16+16) (linear; Vt content already swizzled)
  auto stage = [&](int bf, int k0) {
    const bf16_t* Kg = Kbase + (size_t)(k0 + w * 32 + (lane >> 3)) * 3072
                       + sw_chunk * 8;
    bf16_t* Kl = &Ks[bf][(w * 32) * 64];
#pragma unroll
    for (int i = 0; i < 4; ++i)
      gload_lds16(Kg + (size_t)i * 8 * 3072, Kl + i * 8 * 64);
    const bf16_t* Vg = Vbase + (size_t)(w * 16 + (lane >> 4)) * SEQ + k0
                       + (lane & 15) * 8;
    bf16_t* Vl = &Vs[bf][(w * 16) * 128];
#pragma unroll
    for (int i = 0; i < 4; ++i)
      gload_lds16(Vg + (size_t)i * 4 * SEQ, Vl + i * 4 * 128);
  };

  stage(0, 0);
  __syncthreads();
  int cur = 0;
  for (int kt = 0; kt < ntiles; ++kt) {
    if (kt + 1 < ntiles) stage(cur ^ 1, (kt + 1) * 128);
    if (kt == ntiles - 1)
      attn_tile<true>(Ks[cur], Vs[cur], kt * 128, w + 1, w, quad, l16,
                      krow, xr0, tokb, qf, onev, oacc, lacc);
    else
      attn_tile<false>(Ks[cur], Vs[cur], kt * 128, 4, w, quad, l16,
                       krow, xr0, tokb, qf, onev, oacc, lacc);
    __syncthreads();   // drains next-tile staging (flew during compute)
    cur ^= 1;
  }

  // normalize and write attn output [tok][h*64+d]; 4 consecutive d per lane
#pragma unroll
  for (int mi = 0; mi < 2; ++mi) {
    const float invl = 1.0f / lacc[mi][0];
    const size_t row =
        (size_t)(b * SEQ + qrow0 + mi * 16 + l16) * DMODEL + h * 64;
#pragma unroll
    for (int nd = 0; nd < 4; ++nd) {
      union { ushort4 u; bf16_t bv[4]; } cv;
#pragma unroll
      for (int r = 0; r < 4; ++r)
        cv.bv[r] = (bf16_t)(oacc[mi][nd][r] * invl);
      *(ushort4*)(attnb + row + nd * 16 + quad * 4) = cv.u;
    }
  }
}

// ---------------------------------------------------------------------------
extern "C" void kernel_launch(void* const* d_in, const int* in_sizes, int n_in,
                              void* d_out, int out_size, void* d_ws, size_t ws_size,
                              hipStream_t stream) {
  const int*   tokens = (const int*)d_in[0];
  const float* emb    = (const float*)d_in[1];
  const float* pos    = (const float*)d_in[2];
  const float* ln1g   = (const float*)d_in[3];
  const float* ln1b   = (const float*)d_in[4];
  const float* ln2g   = (const float*)d_in[5];
  const float* ln2b   = (const float*)d_in[6];
  const float* ln3g   = (const float*)d_in[7];
  const float* ln3b   = (const float*)d_in[8];
  const float* Wq     = (const float*)d_in[9];
  const float* bq     = (const float*)d_in[10];
  const float* Wk     = (const float*)d_in[11];
  const float* bk     = (const float*)d_in[12];
  const float* Wv     = (const float*)d_in[13];
  const float* bv     = (const float*)d_in[14];
  const float* Wo     = (const float*)d_in[15];
  const float* bo     = (const float*)d_in[16];
  const float* W1     = (const float*)d_in[17];
  const float* b1     = (const float*)d_in[18];
  const float* W2     = (const float*)d_in[19];
  const float* b2     = (const float*)d_in[20];
  float* out = (float*)d_out;

  char* p = (char*)d_ws;
  auto alloc = [&](size_t bytes) {
    char* q = p; p += (bytes + 255) & ~(size_t)255; return q;
  };
  float*  x_ln   = (float*)alloc((size_t)NTOK * DMODEL * 4);
  bf16_t* x_lnb  = (bf16_t*)alloc((size_t)NTOK * DMODEL * 2);
  bf16_t* WqkvT  = (bf16_t*)alloc((size_t)3072 * 1024 * 2);
  float*  bqkv   = (float*)alloc(3072 * 4);
  bf16_t* WoT    = (bf16_t*)alloc((size_t)1024 * 1024 * 2);
  bf16_t* W1T    = (bf16_t*)alloc((size_t)4096 * 1024 * 2);
  bf16_t* W2T    = (bf16_t*)alloc((size_t)1024 * 4096 * 2);
  bf16_t* qkvb   = (bf16_t*)alloc((size_t)NTOK * 3072 * 2);
  bf16_t* Vtb    = (bf16_t*)alloc((size_t)32 * 64 * SEQ * 2);
  bf16_t* attnb  = (bf16_t*)alloc((size_t)NTOK * DMODEL * 2);
  float*  attn_o = (float*)alloc((size_t)NTOK * DMODEL * 4);
  float*  x2     = (float*)alloc((size_t)NTOK * DMODEL * 4);
  bf16_t* x3b    = (bf16_t*)alloc((size_t)NTOK * DMODEL * 2);
  bf16_t* hbuf   = (bf16_t*)alloc((size_t)NTOK * 4096 * 2);

  // weight prep (re-done every call; ws is re-poisoned by harness)
  wtrans_kernel<<<dim3(16, 16), 256, 0, stream>>>(Wq, WqkvT,                 1024, 1024);
  wtrans_kernel<<<dim3(16, 16), 256, 0, stream>>>(Wk, WqkvT + 1024ull * 1024, 1024, 1024);
  wtrans_kernel<<<dim3(16, 16), 256, 0, stream>>>(Wv, WqkvT + 2048ull * 1024, 1024, 1024);
  wtrans_kernel<<<dim3(16, 16), 256, 0, stream>>>(Wo, WoT, 1024, 1024);
  wtrans_kernel<<<dim3(64, 16), 256, 0, stream>>>(W1, W1T, 1024, 4096);
  wtrans_kernel<<<dim3(16, 64), 256, 0, stream>>>(W2, W2T, 4096, 1024);
  pack_bias_kernel<<<4, 256, 0, stream>>>(bq, bk, bv, bqkv);

  // embed + LN1
  ln1_kernel<<<NTOK, 256, 0, stream>>>(tokens, emb, pos, ln1g, ln1b, x_ln, x_lnb);

  // QKV projection (packed N=3072)
  gemm_bt<EPI_BF16><<<dim3(32, 24), 256, 0, stream>>>(
      x_lnb, WqkvT, bqkv, nullptr, qkvb, nullptr, NTOK, 3072, 1024);

  // V transpose (pre-swizzled chunks) for LDS-staged PV MFMA
  vtrans_kernel<<<dim3(16, 32), 256, 0, stream>>>(qkvb, Vtb);

  // flash attention (128-row strips, balanced pairing, dbuf LDS staging)
  attn_kernel<<<dim3(32, 16), 256, 0, stream>>>(qkvb, Vtb, tokens, attnb);

  // output projection (N=1024: 128x64 tiles, BK=128 -> 8 iterations)
  gemm_bt64<EPI_F32><<<dim3(32, 16), 256, 0, stream>>>(
      attnb, WoT, bo, nullptr, nullptr, attn_o, NTOK, 1024, 1024);

  // x2 = x_ln + LN2(attn_out);  x3b = bf16(LN3(x2))
  ln23_kernel<<<NTOK, 256, 0, stream>>>(attn_o, x_ln, ln2g, ln2b, ln3g, ln3b, x2, x3b);

  // FFN up + fast GELU
  gemm_bt<EPI_GELU><<<dim3(32, 32), 256, 0, stream>>>(
      x3b, W1T, b1, nullptr, hbuf, nullptr, NTOK, 4096, 1024);

  // FFN down + residual -> out (N=1024: 128x64 tiles, BK=128 -> 32 iters)
  gemm_bt64<EPI_RES><<<dim3(32, 16), 256, 0, stream>>>(
      hbuf, W2T, b2, x2, nullptr, out, NTOK, 1024, 4096);

  (void)in_sizes; (void)n_in; (void)out_size; (void)ws_size;
}

// Round 9
// 470.706 us; speedup vs baseline: 1.1261x; 1.1261x over previous
//
#include <hip/hip_runtime.h>
#include <cstdint>
#include <cstddef>

// ---------------------------------------------------------------------------
// TransformerEncoderLayer on MI355X (gfx950)
// B=2, S=2048, D_MODEL=1024, 16 heads x 64, VOCAB=32000, PAD=0
// bf16 MFMA for all GEMMs + flash attention; fp32 LN / residual streams.
// R13 = R11 (BK=128 of R12 retired: conflicts doubled, -24us regression)
//     + XOR chunk-swizzle on BOTH GEMM kernels' A/B staging (the attn-K
//     proven pattern): global source chunk (lane&7)^((lane>>3)&7), linear
//     LDS dest (global_load_lds rule), fragment read at chunk
//     (kc*4+quad)^(l16&7). Fixes the structural 16-way bank conflict of
//     the 128B-row-stride tile (R11 FFN-down: 1.9e7 conflict cycles ~= 40%
//     of kernel). No sync-structure changes.
// ---------------------------------------------------------------------------

#define SEQ     2048
#define NTOK    4096          // B*S
#define DMODEL  1024
#define NHEAD   16
#define DHEAD   64
#define MASKV   (-30.0f)      // soft mask: exp(-30)~1e-13, exact softmax ratios
#define LN_EPS  1e-5f

typedef __bf16 bf16_t;
typedef __bf16 bf16x8 __attribute__((ext_vector_type(8)));
typedef float  f32x4  __attribute__((ext_vector_type(4)));

#define MFMA_BF16(a,b,c) __builtin_amdgcn_mfma_f32_16x16x32_bf16((a),(b),(c),0,0,0)

__device__ __forceinline__ void gload_lds16(const void* g, void* l) {
  __builtin_amdgcn_global_load_lds(
      (__attribute__((address_space(1))) void*)(g),
      (__attribute__((address_space(3))) void*)(l), 16, 0, 0);
}

// ---------------- weight transpose+convert: W[K][N] f32 -> WT[N][K] bf16 ----
__global__ __launch_bounds__(256)
void wtrans_kernel(const float* __restrict__ W, bf16_t* __restrict__ WT,
                   int K, int N) {
  __shared__ float tile[64][65];
  const int n0 = blockIdx.x * 64, k0 = blockIdx.y * 64;
  const int c = threadIdx.x & 63, rb = threadIdx.x >> 6;
#pragma unroll
  for (int i = 0; i < 16; ++i) {
    int r = i * 4 + rb;
    tile[r][c] = W[(size_t)(k0 + r) * N + n0 + c];
  }
  __syncthreads();
#pragma unroll
  for (int i = 0; i < 16; ++i) {
    int r = i * 4 + rb;                       // output row (n), col (k)
    WT[(size_t)(n0 + r) * K + k0 + c] = (bf16_t)tile[c][r];
  }
}

__global__ __launch_bounds__(256)
void pack_bias_kernel(const float* __restrict__ bq, const float* __restrict__ bk,
                      const float* __restrict__ bv, float* __restrict__ o) {
  int i = blockIdx.x * 256 + threadIdx.x;
  if (i < 1024) { o[i] = bq[i]; o[1024 + i] = bk[i]; o[2048 + i] = bv[i]; }
}

// ---------------- embed + pos + LN1 -> x_ln f32, x_ln bf16 ------------------
__global__ __launch_bounds__(256)
void ln1_kernel(const int* __restrict__ tokens, const float* __restrict__ emb,
                const float* __restrict__ pos, const float* __restrict__ g,
                const float* __restrict__ bb, float* __restrict__ xln,
                bf16_t* __restrict__ xlnb) {
  __shared__ float red[8];
  const int t = blockIdx.x;
  const int s = t & (SEQ - 1);
  const int tok = tokens[t];
  const int d0 = threadIdx.x * 4;
  const int w = threadIdx.x >> 6, lane = threadIdx.x & 63;

  float4 e  = *(const float4*)(emb + (size_t)tok * DMODEL + d0);
  float4 pp = *(const float4*)(pos + (size_t)s   * DMODEL + d0);
  float x0 = e.x + pp.x, x1 = e.y + pp.y, x2v = e.z + pp.z, x3v = e.w + pp.w;
  float s1 = x0 + x1 + x2v + x3v;
  float s2 = x0*x0 + x1*x1 + x2v*x2v + x3v*x3v;
#pragma unroll
  for (int o = 32; o >= 1; o >>= 1) { s1 += __shfl_xor(s1, o); s2 += __shfl_xor(s2, o); }
  if (lane == 0) { red[w] = s1; red[4 + w] = s2; }
  __syncthreads();
  s1 = red[0] + red[1] + red[2] + red[3];
  s2 = red[4] + red[5] + red[6] + red[7];
  float mean = s1 * (1.0f / DMODEL);
  float var  = s2 * (1.0f / DMODEL) - mean * mean;
  float inv  = rsqrtf(var + LN_EPS);
  float4 gv = *(const float4*)(g + d0);
  float4 bv = *(const float4*)(bb + d0);
  float y0 = (x0  - mean) * inv * gv.x + bv.x;
  float y1 = (x1  - mean) * inv * gv.y + bv.y;
  float y2 = (x2v - mean) * inv * gv.z + bv.z;
  float y3 = (x3v - mean) * inv * gv.w + bv.w;
  *(float4*)(xln + (size_t)t * DMODEL + d0) = make_float4(y0, y1, y2, y3);
  union { ushort4 u; bf16_t b[4]; } cv;
  cv.b[0] = (bf16_t)y0; cv.b[1] = (bf16_t)y1; cv.b[2] = (bf16_t)y2; cv.b[3] = (bf16_t)y3;
  *(ushort4*)(xlnb + (size_t)t * DMODEL + d0) = cv.u;
}

// -------- x2 = x_ln + LN2(attn_out); x3b = bf16(LN3(x2)) --------------------
__global__ __launch_bounds__(256)
void ln23_kernel(const float* __restrict__ ao, const float* __restrict__ xln,
                 const float* __restrict__ g2, const float* __restrict__ bb2,
                 const float* __restrict__ g3, const float* __restrict__ bb3,
                 float* __restrict__ x2o, bf16_t* __restrict__ x3b) {
  __shared__ float red[8];
  const int t = blockIdx.x;
  const int d0 = threadIdx.x * 4;
  const int w = threadIdx.x >> 6, lane = threadIdx.x & 63;

  float4 a = *(const float4*)(ao + (size_t)t * DMODEL + d0);
  float s1 = a.x + a.y + a.z + a.w;
  float s2 = a.x*a.x + a.y*a.y + a.z*a.z + a.w*a.w;
#pragma unroll
  for (int o = 32; o >= 1; o >>= 1) { s1 += __shfl_xor(s1, o); s2 += __shfl_xor(s2, o); }
  if (lane == 0) { red[w] = s1; red[4 + w] = s2; }
  __syncthreads();
  s1 = red[0] + red[1] + red[2] + red[3];
  s2 = red[4] + red[5] + red[6] + red[7];
  float mean = s1 * (1.0f / DMODEL);
  float var  = s2 * (1.0f / DMODEL) - mean * mean;
  float inv  = rsqrtf(var + LN_EPS);
  float4 gv = *(const float4*)(g2 + d0);
  float4 bv = *(const float4*)(bb2 + d0);
  float4 xv = *(const float4*)(xln + (size_t)t * DMODEL + d0);
  float y0 = xv.x + (a.x - mean) * inv * gv.x + bv.x;
  float y1 = xv.y + (a.y - mean) * inv * gv.y + bv.y;
  float y2 = xv.z + (a.z - mean) * inv * gv.z + bv.z;
  float y3 = xv.w + (a.w - mean) * inv * gv.w + bv.w;
  *(float4*)(x2o + (size_t)t * DMODEL + d0) = make_float4(y0, y1, y2, y3);

  // second LN (LN3) on x2
  float t1 = y0 + y1 + y2 + y3;
  float t2 = y0*y0 + y1*y1 + y2*y2 + y3*y3;
#pragma unroll
  for (int o = 32; o >= 1; o >>= 1) { t1 += __shfl_xor(t1, o); t2 += __shfl_xor(t2, o); }
  __syncthreads();                         // all phase-1 reads of red[] done
  if (lane == 0) { red[w] = t1; red[4 + w] = t2; }
  __syncthreads();
  t1 = red[0] + red[1] + red[2] + red[3];
  t2 = red[4] + red[5] + red[6] + red[7];
  float mean2 = t1 * (1.0f / DMODEL);
  float var2  = t2 * (1.0f / DMODEL) - mean2 * mean2;
  float inv2  = rsqrtf(var2 + LN_EPS);
  float4 gv3 = *(const float4*)(g3 + d0);
  float4 bv3 = *(const float4*)(bb3 + d0);
  union { ushort4 u; bf16_t b[4]; } cv;
  cv.b[0] = (bf16_t)((y0 - mean2) * inv2 * gv3.x + bv3.x);
  cv.b[1] = (bf16_t)((y1 - mean2) * inv2 * gv3.y + bv3.y);
  cv.b[2] = (bf16_t)((y2 - mean2) * inv2 * gv3.z + bv3.z);
  cv.b[3] = (bf16_t)((y3 - mean2) * inv2 * gv3.w + bv3.w);
  *(ushort4*)(x3b + (size_t)t * DMODEL + d0) = cv.u;
}

// ---------------- generic TN bf16 GEMM: C = A[M,K] @ B[N,K]^T + bias --------
// EPI: 0 = bf16 store, 1 = f32 store, 2 = tanh-GELU + bf16, 3 = +res f32
// A/B tiles staged with XOR chunk-swizzle (source pre-swizzled, LDS linear):
// LDS[r][c] holds global chunk c^(r&7); fragment read XORs with l16&7.
constexpr int EPI_BF16 = 0, EPI_F32 = 1, EPI_GELU = 2, EPI_RES = 3;

// gelu(v) ~= v * sigmoid(1.5957691*v + 0.07135482*v^3); max err ~3e-4
__device__ __forceinline__ float gelu_fast(float v) {
  float u = v * (1.5957691216f + 0.0713548163f * v * v);
  return v * __frcp_rn(1.0f + __expf(-u));
}

template <int EPI>
__global__ __launch_bounds__(256, 4)
void gemm_bt(const bf16_t* __restrict__ A, const bf16_t* __restrict__ B,
             const float* __restrict__ bias, const float* __restrict__ res,
             bf16_t* __restrict__ obf, float* __restrict__ of32,
             int M, int N, int K) {
  __shared__ __attribute__((aligned(16))) bf16_t As[128 * 64];
  __shared__ __attribute__((aligned(16))) bf16_t Bs[128 * 64];
  const int tid = threadIdx.x;
  const int w = tid >> 6, lane = tid & 63;
  const int quad = lane >> 4, l16 = lane & 15;
  const int m0 = blockIdx.x * 128, n0 = blockIdx.y * 128;
  const int wm = (w >> 1) * 64, wn = (w & 1) * 64;
  const int sw = (lane & 7) ^ ((lane >> 3) & 7);   // source chunk swizzle
  const int xr = l16 & 7;                          // read-side XOR (row&7)
  const size_t Kz = (size_t)K;

  f32x4 acc[4][4] = {};

  const bf16_t* Ag = A + (size_t)(m0 + w * 32 + (lane >> 3)) * Kz + sw * 8;
  const bf16_t* Bg = B + (size_t)(n0 + w * 32 + (lane >> 3)) * Kz + sw * 8;
  bf16_t* Asw = &As[(w * 32) * 64];
  bf16_t* Bsw = &Bs[(w * 32) * 64];

  for (int k0 = 0; k0 < K; k0 += 64) {
#pragma unroll
    for (int i = 0; i < 4; ++i) {
      gload_lds16(Ag + (size_t)i * 8 * Kz + k0, Asw + i * 8 * 64);
      gload_lds16(Bg + (size_t)i * 8 * Kz + k0, Bsw + i * 8 * 64);
    }
    __syncthreads();
#pragma unroll
    for (int kc = 0; kc < 2; ++kc) {
      bf16x8 af[4], bfr[4];
#pragma unroll
      for (int i = 0; i < 4; ++i) {
        af[i]  = *(const bf16x8*)&As[(wm + i * 16 + l16) * 64
                                     + (((kc * 4 + quad) ^ xr) << 3)];
        bfr[i] = *(const bf16x8*)&Bs[(wn + i * 16 + l16) * 64
                                     + (((kc * 4 + quad) ^ xr) << 3)];
      }
#pragma unroll
      for (int mi = 0; mi < 4; ++mi)
#pragma unroll
        for (int ni = 0; ni < 4; ++ni)
          acc[mi][ni] = MFMA_BF16(af[mi], bfr[ni], acc[mi][ni]);
    }
    __syncthreads();
  }

#pragma unroll
  for (int ni = 0; ni < 4; ++ni) {
    const int col = n0 + wn + ni * 16 + l16;
    const float bv = bias[col];
#pragma unroll
    for (int mi = 0; mi < 4; ++mi) {
#pragma unroll
      for (int r = 0; r < 4; ++r) {
        const int row = m0 + wm + mi * 16 + quad * 4 + r;
        float v = acc[mi][ni][r] + bv;
        if constexpr (EPI == EPI_GELU)
          v = gelu_fast(v);
        if constexpr (EPI == EPI_RES)
          v += res[(size_t)row * N + col];
        if constexpr (EPI == EPI_BF16 || EPI == EPI_GELU)
          obf[(size_t)row * N + col] = (bf16_t)v;
        else
          of32[(size_t)row * N + col] = v;
      }
    }
  }
}

// -------- 128x64-tile TN GEMM (for N=1024 GEMMs): 512 blocks, 24KB LDS ------
// Proven single-buffer 2-barrier loop (BK=64), same XOR chunk-swizzle.
template <int EPI>
__global__ __launch_bounds__(256, 4)
void gemm_bt64(const bf16_t* __restrict__ A, const bf16_t* __restrict__ B,
               const float* __restrict__ bias, const float* __restrict__ res,
               bf16_t* __restrict__ obf, float* __restrict__ of32,
               int M, int N, int K) {
  __shared__ __attribute__((aligned(16))) bf16_t As[128 * 64];
  __shared__ __attribute__((aligned(16))) bf16_t Bs[64 * 64];
  const int tid = threadIdx.x;
  const int w = tid >> 6, lane = tid & 63;
  const int quad = lane >> 4, l16 = lane & 15;
  const int m0 = blockIdx.x * 128, n0 = blockIdx.y * 64;
  const int wm = w * 32;
  const int sw = (lane & 7) ^ ((lane >> 3) & 7);   // source chunk swizzle
  const int xr = l16 & 7;                          // read-side XOR (row&7)
  const size_t Kz = (size_t)K;

  f32x4 acc[2][4] = {};

  const bf16_t* Ag = A + (size_t)(m0 + w * 32 + (lane >> 3)) * Kz + sw * 8;
  const bf16_t* Bg = B + (size_t)(n0 + w * 16 + (lane >> 3)) * Kz + sw * 8;
  bf16_t* Asw = &As[(w * 32) * 64];
  bf16_t* Bsw = &Bs[(w * 16) * 64];

  for (int k0 = 0; k0 < K; k0 += 64) {
#pragma unroll
    for (int i = 0; i < 4; ++i)
      gload_lds16(Ag + (size_t)i * 8 * Kz + k0, Asw + i * 8 * 64);
#pragma unroll
    for (int i = 0; i < 2; ++i)
      gload_lds16(Bg + (size_t)i * 8 * Kz + k0, Bsw + i * 8 * 64);
    __syncthreads();
#pragma unroll
    for (int kc = 0; kc < 2; ++kc) {
      bf16x8 af[2], bfr[4];
#pragma unroll
      for (int i = 0; i < 2; ++i)
        af[i]  = *(const bf16x8*)&As[(wm + i * 16 + l16) * 64
                                     + (((kc * 4 + quad) ^ xr) << 3)];
#pragma unroll
      for (int i = 0; i < 4; ++i)
        bfr[i] = *(const bf16x8*)&Bs[(i * 16 + l16) * 64
                                     + (((kc * 4 + quad) ^ xr) << 3)];
#pragma unroll
      for (int mi = 0; mi < 2; ++mi)
#pragma unroll
        for (int ni = 0; ni < 4; ++ni)
          acc[mi][ni] = MFMA_BF16(af[mi], bfr[ni], acc[mi][ni]);
    }
    __syncthreads();
  }

#pragma unroll
  for (int ni = 0; ni < 4; ++ni) {
    const int col = n0 + ni * 16 + l16;
    const float bv = bias[col];
#pragma unroll
    for (int mi = 0; mi < 2; ++mi) {
#pragma unroll
      for (int r = 0; r < 4; ++r) {
        const int row = m0 + wm + mi * 16 + quad * 4 + r;
        float v = acc[mi][ni][r] + bv;
        if constexpr (EPI == EPI_GELU)
          v = gelu_fast(v);
        if constexpr (EPI == EPI_RES)
          v += res[(size_t)row * N + col];
        if constexpr (EPI == EPI_BF16 || EPI == EPI_GELU)
          obf[(size_t)row * N + col] = (bf16_t)v;
        else
          of32[(size_t)row * N + col] = v;
      }
    }
  }
}

// ------ V transpose: qkv V-part [tok][h*64+d] -> Vt[bh][d][s], SWIZZLED -----
// Within each 128-key tile, 16B chunk k of d-row is stored at chunk k^(d&7),
// so attn can stage it linearly with global_load_lds and read conflict-free.
__global__ __launch_bounds__(256)
void vtrans_kernel(const bf16_t* __restrict__ qkv, bf16_t* __restrict__ Vt) {
  __shared__ bf16_t tile[128][72];          // [s_local][d]
  const int bh = blockIdx.y;
  const int b = bh >> 4, h = bh & 15;
  const int s0 = blockIdx.x * 128;
  const int c = threadIdx.x & 63, rb = threadIdx.x >> 6;
#pragma unroll
  for (int i = 0; i < 32; ++i) {
    int r = i * 4 + rb;                       // s-local 0..127
    tile[r][c] = qkv[(size_t)(b * SEQ + s0 + r) * 3072 + 2048 + h * 64 + c];
  }
  __syncthreads();
  const int d = threadIdx.x >> 2;             // 0..63
  const int k4 = threadIdx.x & 3;
#pragma unroll
  for (int kk = 0; kk < 4; ++kk) {
    const int k = kk * 4 + k4;                // chunk 0..15 (8 keys each)
    union { uint4 u; bf16_t bv[8]; } vv;
#pragma unroll
    for (int e = 0; e < 8; ++e) vv.bv[e] = tile[k * 8 + e][d];
    *(uint4*)(Vt + (size_t)(bh * 64 + d) * SEQ + s0 + ((k ^ (d & 7)) << 3)) = vv.u;
  }
}

// ---------------- flash attention, causal + key pad mask --------------------
// Per wave, 32 q-rows. Double-buffered LDS staging (2-phase), register
// softmax, no cross-lane ops:
//   S^T = mfma(K, Q) with permuted K rows: block 2c+e, A-row a <- key
//         32c + 8*(a>>2) + 2*(a&3) + e -> lane (quad,l16) holds even keys
//         8*quad+2r in sc[2c][r], odd in sc[2c+1][r]; PV B-fragment dword m
//         = pack(sc[2c][m], sc[2c+1][m]) by construction.
//   pad + causal applied at exp time (token loads off the MFMA path)
//   O^T += mfma(V^T, P^T);  l via ones-MFMA.

__device__ __forceinline__ unsigned pack2_bf16(float e, float o) {
  union { bf16_t b; unsigned short s; } lo, hi;
  lo.b = (bf16_t)e; hi.b = (bf16_t)o;
  return (unsigned)lo.s | ((unsigned)hi.s << 16);
}

__device__ __forceinline__ int tok_at(const int4& a, const int4& b, int j) {
  switch (j) {
    case 0: return a.x; case 1: return a.y; case 2: return a.z; case 3: return a.w;
    case 4: return b.x; case 5: return b.y; case 6: return b.z; default: return b.w;
  }
}

template <bool DIAG>
__device__ __forceinline__ void attn_tile(
    const bf16_t* __restrict__ Ksb, const bf16_t* __restrict__ Vsb,
    int k0, int chunkCnt, int w, int quad, int l16, int krow, int xr0,
    const int* __restrict__ tokb,
    const bf16x8 (&qf)[2][2], bf16x8 onev,
    f32x4 (&oacc)[2][4], f32x4 (&lacc)[2]) {

  // early token loads for pad mask (used at exp time)
  int4 tA[4], tB[4];
#pragma unroll
  for (int c = 0; c < 4; ++c)
    if (!DIAG || c < chunkCnt) {
      tA[c] = *(const int4*)(tokb + k0 + 32 * c + 8 * quad);
      tB[c] = *(const int4*)(tokb + k0 + 32 * c + 8 * quad + 4);
    }

  f32x4 sc0[8] = {}, sc1[8] = {};

  // S^T = (0.125*Q)K^T : A = permuted K rows from LDS (swizzled chunks)
#pragma unroll
  for (int kc = 0; kc < 2; ++kc)
#pragma unroll
    for (int ni = 0; ni < 8; ++ni)
      if (!DIAG || ni < 2 * chunkCnt) {
        const int r = 32 * (ni >> 1) + (ni & 1) + krow;
        bf16x8 kf = *(const bf16x8*)&Ksb[r * 64
            + (((kc * 4 + quad) ^ (xr0 + (ni & 1))) << 3)];
        sc0[ni] = MFMA_BF16(kf, qf[0][kc], sc0[ni]);
        sc1[ni] = MFMA_BF16(kf, qf[1][kc], sc1[ni]);
      }

  // pad + causal + exp; overwrite sc with P
#pragma unroll
  for (int mi = 0; mi < 2; ++mi) {
    f32x4* sc = mi ? sc1 : sc0;
    const int ql = w * 32 + mi * 16 + l16;       // q local to strip
#pragma unroll
    for (int ni = 0; ni < 8; ++ni)
      if (!DIAG || ni < 2 * chunkCnt) {
        const int c = ni >> 1, e = ni & 1;
#pragma unroll
        for (int r = 0; r < 4; ++r) {
          float v = sc[ni][r];
          if (tok_at(tA[c], tB[c], 2 * r + e) == 0) v += MASKV;
          if (DIAG) {
            int keyl = 32 * c + e + 8 * quad + 2 * r;
            if (keyl > ql) v += MASKV;
          }
          sc[ni][r] = __expf(v);
        }
      }
  }

  // O^T += V^T @ P^T ; l via ones-MFMA (D[r][q] = l[q] for every r).
#pragma unroll
  for (int c = 0; c < 4; ++c)
    if (!DIAG || c < chunkCnt) {
      union { unsigned u[4]; bf16x8 v; } pb0, pb1;
#pragma unroll
      for (int m = 0; m < 4; ++m) {
        pb0.u[m] = pack2_bf16(sc0[2 * c][m], sc0[2 * c + 1][m]);
        pb1.u[m] = pack2_bf16(sc1[2 * c][m], sc1[2 * c + 1][m]);
      }
      lacc[0] = MFMA_BF16(onev, pb0.v, lacc[0]);
      lacc[1] = MFMA_BF16(onev, pb1.v, lacc[1]);
#pragma unroll
      for (int nd = 0; nd < 4; ++nd) {
        bf16x8 vf = *(const bf16x8*)&Vsb[(nd * 16 + l16) * 128
            + (((c * 4 + quad) ^ (l16 & 7)) << 3)];
        oacc[0][nd] = MFMA_BF16(vf, pb0.v, oacc[0][nd]);
        oacc[1][nd] = MFMA_BF16(vf, pb1.v, oacc[1][nd]);
      }
    }
}

__global__ __launch_bounds__(256, 2)
void attn_kernel(const bf16_t* __restrict__ qkv, const bf16_t* __restrict__ Vt,
                 const int* __restrict__ tokens, bf16_t* __restrict__ attnb) {
  __shared__ __attribute__((aligned(16))) bf16_t Ks[2][128 * 64];   // 32 KB
  __shared__ __attribute__((aligned(16))) bf16_t Vs[2][64 * 128];   // 32 KB

  const int tid = threadIdx.x;
  const int w = tid >> 6, lane = tid & 63;
  const int quad = lane >> 4, l16 = lane & 15;
  const int bh = blockIdx.x;
  const int by = (int)blockIdx.y;
  // balanced pairing: CU pair gets strips s and 15-s (17 tiles total)
  const int strip = (by < 8) ? (15 - by) : (by - 8);
  const int b = bh >> 4, h = bh & 15;
  const int ntiles = strip + 1;
  const int qrow0 = strip * 128 + w * 32;    // this wave's 32 q-rows
  const int krow = ((l16 >> 2) << 3) + ((l16 & 3) << 1);
  const int xr0 = (l16 & 3) << 1;            // (permuted row)&7 = xr0 + e
  const int sw_chunk = (lane & 7) ^ ((lane >> 3) & 7);

  const bf16_t* Kbase = qkv + (size_t)b * SEQ * 3072 + 1024 + h * 64;
  const bf16_t* Vbase = Vt + (size_t)bh * 64 * SEQ;   // pre-swizzled content
  const int*    tokb  = tokens + b * SEQ;

  // Q fragments (B-operand: col=q=l16, k=quad*8+j), pre-scaled by 0.125
  bf16x8 qf[2][2];
#pragma unroll
  for (int mi = 0; mi < 2; ++mi) {
    const size_t trow = (size_t)(b * SEQ + qrow0 + mi * 16 + l16) * 3072 + h * 64;
    qf[mi][0] = *(const bf16x8*)(qkv + trow + quad * 8);
    qf[mi][1] = *(const bf16x8*)(qkv + trow + 32 + quad * 8);
  }
#pragma unroll
  for (int mi = 0; mi < 2; ++mi)
#pragma unroll
    for (int kc = 0; kc < 2; ++kc)
#pragma unroll
      for (int j = 0; j < 8; ++j)
        qf[mi][kc][j] = (bf16_t)((float)qf[mi][kc][j] * 0.125f);

  bf16x8 onev;
#pragma unroll
  for (int j = 0; j < 8; ++j) onev[j] = (bf16_t)1.0f;

  f32x4 oacc[2][4] = {};   // O^T: row=d (quad*4+r within nd), col=q (l16)
  f32x4 lacc[2] = {};

  // staging: wave w stages K rows [w*32,w*32+32) (source pre-swizzled chunks)
  // and V d-rows [w*16,w*16+16) (linear; Vt content already swizzled)
  auto stage = [&](int bf, int k0) {
    const bf16_t* Kg = Kbase + (size_t)(k0 + w * 32 + (lane >> 3)) * 3072
                       + sw_chunk * 8;
    bf16_t* Kl = &Ks[bf][(w * 32) * 64];
#pragma unroll
    for (int i = 0; i < 4; ++i)
      gload_lds16(Kg + (size_t)i * 8 * 3072, Kl + i * 8 * 64);
    const bf16_t* Vg = Vbase + (size_t)(w * 16 + (lane >> 4)) * SEQ + k0
                       + (lane & 15) * 8;
    bf16_t* Vl = &Vs[bf][(w * 16) * 128];
#pragma unroll
    for (int i = 0; i < 4; ++i)
      gload_lds16(Vg + (size_t)i * 4 * SEQ, Vl + i * 4 * 128);
  };

  stage(0, 0);
  __syncthreads();
  int cur = 0;
  for (int kt = 0; kt < ntiles; ++kt) {
    if (kt + 1 < ntiles) stage(cur ^ 1, (kt + 1) * 128);
    if (kt == ntiles - 1)
      attn_tile<true>(Ks[cur], Vs[cur], kt * 128, w + 1, w, quad, l16,
                      krow, xr0, tokb, qf, onev, oacc, lacc);
    else
      attn_tile<false>(Ks[cur], Vs[cur], kt * 128, 4, w, quad, l16,
                       krow, xr0, tokb, qf, onev, oacc, lacc);
    __syncthreads();   // drains next-tile staging (flew during compute)
    cur ^= 1;
  }

  // normalize and write attn output [tok][h*64+d]; 4 consecutive d per lane
#pragma unroll
  for (int mi = 0; mi < 2; ++mi) {
    const float invl = 1.0f / lacc[mi][0];
    const size_t row =
        (size_t)(b * SEQ + qrow0 + mi * 16 + l16) * DMODEL + h * 64;
#pragma unroll
    for (int nd = 0; nd < 4; ++nd) {
      union { ushort4 u; bf16_t bv[4]; } cv;
#pragma unroll
      for (int r = 0; r < 4; ++r)
        cv.bv[r] = (bf16_t)(oacc[mi][nd][r] * invl);
      *(ushort4*)(attnb + row + nd * 16 + quad * 4) = cv.u;
    }
  }
}

// ---------------------------------------------------------------------------
extern "C" void kernel_launch(void* const* d_in, const int* in_sizes, int n_in,
                              void* d_out, int out_size, void* d_ws, size_t ws_size,
                              hipStream_t stream) {
  const int*   tokens = (const int*)d_in[0];
  const float* emb    = (const float*)d_in[1];
  const float* pos    = (const float*)d_in[2];
  const float* ln1g   = (const float*)d_in[3];
  const float* ln1b   = (const float*)d_in[4];
  const float* ln2g   = (const float*)d_in[5];
  const float* ln2b   = (const float*)d_in[6];
  const float* ln3g   = (const float*)d_in[7];
  const float* ln3b   = (const float*)d_in[8];
  const float* Wq     = (const float*)d_in[9];
  const float* bq     = (const float*)d_in[10];
  const float* Wk     = (const float*)d_in[11];
  const float* bk     = (const float*)d_in[12];
  const float* Wv     = (const float*)d_in[13];
  const float* bv     = (const float*)d_in[14];
  const float* Wo     = (const float*)d_in[15];
  const float* bo     = (const float*)d_in[16];
  const float* W1     = (const float*)d_in[17];
  const float* b1     = (const float*)d_in[18];
  const float* W2     = (const float*)d_in[19];
  const float* b2     = (const float*)d_in[20];
  float* out = (float*)d_out;

  char* p = (char*)d_ws;
  auto alloc = [&](size_t bytes) {
    char* q = p; p += (bytes + 255) & ~(size_t)255; return q;
  };
  float*  x_ln   = (float*)alloc((size_t)NTOK * DMODEL * 4);
  bf16_t* x_lnb  = (bf16_t*)alloc((size_t)NTOK * DMODEL * 2);
  bf16_t* WqkvT  = (bf16_t*)alloc((size_t)3072 * 1024 * 2);
  float*  bqkv   = (float*)alloc(3072 * 4);
  bf16_t* WoT    = (bf16_t*)alloc((size_t)1024 * 1024 * 2);
  bf16_t* W1T    = (bf16_t*)alloc((size_t)4096 * 1024 * 2);
  bf16_t* W2T    = (bf16_t*)alloc((size_t)1024 * 4096 * 2);
  bf16_t* qkvb   = (bf16_t*)alloc((size_t)NTOK * 3072 * 2);
  bf16_t* Vtb    = (bf16_t*)alloc((size_t)32 * 64 * SEQ * 2);
  bf16_t* attnb  = (bf16_t*)alloc((size_t)NTOK * DMODEL * 2);
  float*  attn_o = (float*)alloc((size_t)NTOK * DMODEL * 4);
  float*  x2     = (float*)alloc((size_t)NTOK * DMODEL * 4);
  bf16_t* x3b    = (bf16_t*)alloc((size_t)NTOK * DMODEL * 2);
  bf16_t* hbuf   = (bf16_t*)alloc((size_t)NTOK * 4096 * 2);

  // weight prep (re-done every call; ws is re-poisoned by harness)
  wtrans_kernel<<<dim3(16, 16), 256, 0, stream>>>(Wq, WqkvT,                 1024, 1024);
  wtrans_kernel<<<dim3(16, 16), 256, 0, stream>>>(Wk, WqkvT + 1024ull * 1024, 1024, 1024);
  wtrans_kernel<<<dim3(16, 16), 256, 0, stream>>>(Wv, WqkvT + 2048ull * 1024, 1024, 1024);
  wtrans_kernel<<<dim3(16, 16), 256, 0, stream>>>(Wo, WoT, 1024, 1024);
  wtrans_kernel<<<dim3(64, 16), 256, 0, stream>>>(W1, W1T, 1024, 4096);
  wtrans_kernel<<<dim3(16, 64), 256, 0, stream>>>(W2, W2T, 4096, 1024);
  pack_bias_kernel<<<4, 256, 0, stream>>>(bq, bk, bv, bqkv);

  // embed + LN1
  ln1_kernel<<<NTOK, 256, 0, stream>>>(tokens, emb, pos, ln1g, ln1b, x_ln, x_lnb);

  // QKV projection (packed N=3072)
  gemm_bt<EPI_BF16><<<dim3(32, 24), 256, 0, stream>>>(
      x_lnb, WqkvT, bqkv, nullptr, qkvb, nullptr, NTOK, 3072, 1024);

  // V transpose (pre-swizzled chunks) for LDS-staged PV MFMA
  vtrans_kernel<<<dim3(16, 32), 256, 0, stream>>>(qkvb, Vtb);

  // flash attention (128-row strips, balanced pairing, dbuf LDS staging)
  attn_kernel<<<dim3(32, 16), 256, 0, stream>>>(qkvb, Vtb, tokens, attnb);

  // output projection (N=1024: 128x64 tiles -> 512 blocks)
  gemm_bt64<EPI_F32><<<dim3(32, 16), 256, 0, stream>>>(
      attnb, WoT, bo, nullptr, nullptr, attn_o, NTOK, 1024, 1024);

  // x2 = x_ln + LN2(attn_out);  x3b = bf16(LN3(x2))
  ln23_kernel<<<NTOK, 256, 0, stream>>>(attn_o, x_ln, ln2g, ln2b, ln3g, ln3b, x2, x3b);

  // FFN up + fast GELU
  gemm_bt<EPI_GELU><<<dim3(32, 32), 256, 0, stream>>>(
      x3b, W1T, b1, nullptr, hbuf, nullptr, NTOK, 4096, 1024);

  // FFN down + residual -> out (N=1024: 128x64 tiles -> 512 blocks)
  gemm_bt64<EPI_RES><<<dim3(32, 16), 256, 0, stream>>>(
      hbuf, W2T, b2, x2, nullptr, out, NTOK, 1024, 4096);

  (void)in_sizes; (void)n_in; (void)out_size; (void)ws_size;
}